// Round 9
// baseline (465.871 us; speedup 1.0000x reference)
//
#include <hip/hip_runtime.h>
#include <math.h>

// GAT 2-layer: N=50000 nodes, E=800000 edges, heads=1
// dims: 128 -> 128 (BN+ReLU) -> 112 (BN)
#define NN 50000
#define NPAD 50048               // 782 * 64, MFMA row tiles
#define NE 800000
#define SCAN_B 256
#define SCAN_NBLK ((NN + SCAN_B - 1) / SCAN_B)   // 196
#define AGG_NBLK 3200            // 3200 blocks * 16 quarters = 51200 slots >= NN
#define NBUCK 1024               // CSR fill coarse buckets
#define BWID 49                  // ceil(NN / NBUCK): dst-range width per bucket

typedef __attribute__((ext_vector_type(8))) short bf16x8;           // MFMA A/B frag
typedef __attribute__((ext_vector_type(4))) float f32x4;            // MFMA C/D frag
typedef __attribute__((ext_vector_type(8))) unsigned short u16x8;   // 16B gather / bf16 store

__device__ __forceinline__ unsigned short f2bf(float x) {
    unsigned u = __float_as_uint(x);
    u += 0x7fffu + ((u >> 16) & 1);              // round-to-nearest-even
    return (unsigned short)(u >> 16);
}
__device__ __forceinline__ float bf2f(unsigned short h) {
    return __uint_as_float(((unsigned)h) << 16);
}

// per-edge logit+exp from a packed record, computed INSIDE the aggregate (layer-select
// by template). als[src] is a 16-lane broadcast gather against a 200KB L2-resident array.
template<int LAYER>
__device__ __forceinline__ float edge_ex(uint2 r, float aldv, const float* __restrict__ als)
{
    float ae = bf2f((unsigned short)(LAYER ? (r.y & 0xffffu) : (r.x >> 16)));
    float a = als[r.x & 0xffffu] + aldv + ae;
    a = a > 0.f ? a : 0.2f * a;
    return __expf(a);
}

// ---------------- init: deg/stats/hist zero + ve fold + W split-transpose ----------------
// ve[0..7] = We0 @ a_edge0 ; ve[8..15] = We1 @ a_edge1   (heads=1 folding)
__global__ void k_init_cvt(int* __restrict__ deg, float* __restrict__ stats,
                           int* __restrict__ hist, int* __restrict__ binCur,
                           const float* __restrict__ We0, const float* __restrict__ ae0,
                           const float* __restrict__ We1, const float* __restrict__ ae1,
                           float* __restrict__ ve,
                           const float* __restrict__ W0, const float* __restrict__ W1,
                           unsigned short* __restrict__ Wth0, unsigned short* __restrict__ Wtl0,
                           unsigned short* __restrict__ Wth1, unsigned short* __restrict__ Wtl1)
{
    int idx = blockIdx.x * 256 + threadIdx.x;
    if (idx < NN) deg[idx] = 0;
    if (idx < 512) stats[idx] = 0.f;
    if (idx < 64) { hist[idx] = 0; binCur[idx] = 0; }
    if (idx < 128 * 128) {
        int k = idx / 128, c = idx % 128;
        float v = W0[idx];
        unsigned short hi = f2bf(v);
        Wth0[c * 128 + k] = hi;
        Wtl0[c * 128 + k] = f2bf(v - bf2f(hi));
    } else if (idx < 128 * 128 + 128 * 112) {
        int i2 = idx - 128 * 128;
        int k = i2 / 112, c = i2 % 112;
        float v = W1[i2];
        unsigned short hi = f2bf(v);
        Wth1[c * 128 + k] = hi;
        Wtl1[c * 128 + k] = f2bf(v - bf2f(hi));
    }
    if (blockIdx.x == gridDim.x - 1) {
        int j = threadIdx.x;
        if (j < 8) {
            float s = 0.f;
            for (int c = 0; c < 128; ++c) s += We0[j * 128 + c] * ae0[c];
            ve[j] = s;
        } else if (j < 16) {
            int jj = j - 8;
            float s = 0.f;
            for (int c = 0; c < 112; ++c) s += We1[jj * 112 + c] * ae1[c];
            ve[8 + jj] = s;
        }
    }
}

// ---------------- CSR build ----------------
// Pure degree count, fire-and-forget atomics (rank is recomputed locally in fill phase 2).
__global__ void k_deg(const int* __restrict__ dst, int* __restrict__ deg, int E_)
{
    int i = blockIdx.x * blockDim.x + threadIdx.x;
    int e = i * 4;
    if (e + 4 <= E_) {
        int4 dd = *reinterpret_cast<const int4*>(dst + e);
        atomicAdd(&deg[dd.x], 1);
        atomicAdd(&deg[dd.y], 1);
        atomicAdd(&deg[dd.z], 1);
        atomicAdd(&deg[dd.w], 1);
    } else {
        for (; e < E_; ++e) atomicAdd(&deg[dst[e]], 1);
    }
}

// block reduce for rp-scan partials + 64-bin degree histogram (LDS-aggregated).
// bin = 63 - min(deg,63): ascending bin == DESCENDING degree for the balance sort.
__global__ void k_scan1(const int* __restrict__ deg, int* __restrict__ partial,
                        int* __restrict__ hist)
{
    __shared__ int sm[SCAN_B];
    __shared__ int lh[64];
    int t = threadIdx.x;
    if (t < 64) lh[t] = 0;
    int idx = blockIdx.x * SCAN_B + t;
    int d = (idx < NN) ? deg[idx] : 0;
    sm[t] = d;
    __syncthreads();
    if (idx < NN) atomicAdd(&lh[63 - (d < 63 ? d : 63)], 1);
    #pragma unroll
    for (int off = SCAN_B / 2; off > 0; off >>= 1) {
        if (t < off) sm[t] += sm[t + off];
        __syncthreads();
    }
    if (t == 0) partial[blockIdx.x] = sm[0];
    if (t < 64 && lh[t]) atomicAdd(&hist[t], lh[t]);
}

// fused stage 2+3: per-block prefix over partials, local scan -> rp;
// then degree-sort scatter of {node, beg, end} uint4 records into ordq[].
__global__ void k_scan3(const int* __restrict__ deg, const int* __restrict__ partial,
                        int* __restrict__ rp, const int* __restrict__ hist,
                        int* __restrict__ binCur, uint4* __restrict__ ordq)
{
    __shared__ int sm[SCAN_B];
    __shared__ int pbase;
    __shared__ int lh[64], lrsv[64], lstart[64];
    int t = threadIdx.x;
    int pv = (t < SCAN_NBLK && t < blockIdx.x) ? partial[t] : 0;
    sm[t] = pv;
    __syncthreads();
    #pragma unroll
    for (int off = SCAN_B / 2; off > 0; off >>= 1) {
        if (t < off) sm[t] += sm[t + off];
        __syncthreads();
    }
    if (t == 0) pbase = sm[0];
    __syncthreads();
    int idx = blockIdx.x * SCAN_B + t;
    int v = (idx < NN) ? deg[idx] : 0;
    sm[t] = v;
    __syncthreads();
    #pragma unroll
    for (int off = 1; off < SCAN_B; off <<= 1) {
        int u = (t >= off) ? sm[t - off] : 0;
        __syncthreads();
        sm[t] += u;
        __syncthreads();
    }
    int excl = pbase + ((t == 0) ? 0 : sm[t - 1]);
    if (idx < NN) rp[idx] = excl;
    if (idx == NN - 1) rp[NN] = excl + v;

    // ---- degree-sort scatter of {node, beg, end} ----
    if (t < 64) lh[t] = 0;
    __syncthreads();
    int b = 0, lr = 0;
    if (idx < NN) {
        b = 63 - (v < 63 ? v : 63);
        lr = atomicAdd(&lh[b], 1);
    }
    __syncthreads();
    if (t < 64) {
        lrsv[t] = lh[t] ? atomicAdd(&binCur[t], lh[t]) : 0;
        int s = 0;
        for (int i = 0; i < t; ++i) s += hist[i];
        lstart[t] = s;
    }
    __syncthreads();
    if (idx < NN) {
        uint4 rec;
        rec.x = (unsigned)idx;
        rec.y = (unsigned)excl;
        rec.z = (unsigned)(excl + v);
        rec.w = 0u;
        ordq[lstart[b] + lrsv[b] + lr] = rec;
    }
}

// ---------------- bucket cursor init: bcur[b] = rp[min(b*BWID, NN)] ----------------
__global__ void k_binit(const int* __restrict__ rp, int* __restrict__ bcur)
{
    int b = blockIdx.x * blockDim.x + threadIdx.x;
    if (b < NBUCK) {
        int nb = b * BWID;
        bcur[b] = rp[nb < NN ? nb : NN];
    }
}

// ---------------- fill phase 1: append {src16|a0, dst16|a1} to coarse dst-buckets --------
// Concurrent atomics on a bucket cursor hand out ADJACENT positions -> writes densify
// into full cache lines (vs. round-8's 64B line event per 8B CSR-scattered record).
__global__ void k_fill_p1(const int* __restrict__ src, const int* __restrict__ dst,
                          const float* __restrict__ eatt, const float* __restrict__ ve,
                          int* __restrict__ bcur, uint2* __restrict__ tmp, int E_)
{
    int i = blockIdx.x * blockDim.x + threadIdx.x;
    int e = i * 4;
    if (e >= E_) return;
    int4 ss = *reinterpret_cast<const int4*>(src + e);
    int4 dd = *reinterpret_cast<const int4*>(dst + e);
    const float4* ea = reinterpret_cast<const float4*>(eatt + (size_t)e * 8);

    float v0 = ve[0], v1 = ve[1], v2 = ve[2], v3 = ve[3];
    float v4 = ve[4], v5 = ve[5], v6 = ve[6], v7 = ve[7];
    float w0 = ve[8], w1 = ve[9], w2 = ve[10], w3 = ve[11];
    float w4 = ve[12], w5 = ve[13], w6 = ve[14], w7 = ve[15];

    int s4[4] = {ss.x, ss.y, ss.z, ss.w};
    int d4[4] = {dd.x, dd.y, dd.z, dd.w};
    #pragma unroll
    for (int k = 0; k < 4; ++k) {
        float4 u0 = ea[2 * k], u1 = ea[2 * k + 1];
        float a0 = u0.x * v0 + u0.y * v1 + u0.z * v2 + u0.w * v3
                 + u1.x * v4 + u1.y * v5 + u1.z * v6 + u1.w * v7;
        float a1 = u0.x * w0 + u0.y * w1 + u0.z * w2 + u0.w * w3
                 + u1.x * w4 + u1.y * w5 + u1.z * w6 + u1.w * w7;
        int d = d4[k];
        int pos = atomicAdd(&bcur[d / BWID], 1);
        uint2 rec;
        rec.x = (unsigned)s4[k] | ((unsigned)f2bf(a0) << 16);
        rec.y = (unsigned)d     | ((unsigned)f2bf(a1) << 16);
        tmp[pos] = rec;
    }
}

// ---------------- fill phase 2: per-bucket local CSR scatter (contiguous window) ---------
// One block per bucket. Reads its ~780-record region coalesced, recomputes per-dst rank
// via LDS counters (bucket spans BWID dst values), writes final {src|a0, a1} records into
// pk[rp[dst]+rank] -- all inside the SAME contiguous region -> fully line-dense writes.
__global__ void k_fill_p2(const int* __restrict__ rp, const uint2* __restrict__ tmp,
                          uint2* __restrict__ pk)
{
    __shared__ int lcnt[BWID];
    int b = blockIdx.x;
    int t = threadIdx.x;
    int nb0 = b * BWID;
    int nb1 = nb0 + BWID;
    int beg = rp[nb0 < NN ? nb0 : NN];
    int end = rp[nb1 < NN ? nb1 : NN];
    if (t < BWID) lcnt[t] = 0;
    __syncthreads();
    for (int i = beg + t; i < end; i += 256) {
        uint2 r = tmp[i];
        int d = (int)(r.y & 0xffffu);
        int lr = atomicAdd(&lcnt[d - nb0], 1);
        int pos = rp[d] + lr;
        uint2 o;
        o.x = r.x;
        o.y = r.y >> 16;
        pk[pos] = o;
    }
}

// ---------------- MFMA GEMM: one wave = 16 rows x COLS, bf16x3 split precision ----------------
// B (Wth+Wtl) staged in LDS with XOR swizzle; A loads hoisted before the staging barrier.
// BN_IN=false: A is fp32 (input x). BN_IN=true: A is bf16 (h), BN0+ReLU fused on load.
template<int COLS, bool BN_IN>
__launch_bounds__(256, 2)
__global__ void k_gemm_mfma(const void* __restrict__ A,
                            const unsigned short* __restrict__ Wth,
                            const unsigned short* __restrict__ Wtl,
                            unsigned short* __restrict__ out,
                            const float* __restrict__ a_src, const float* __restrict__ a_dst,
                            float* __restrict__ als, float* __restrict__ ald,
                            const float* __restrict__ bsum, const float* __restrict__ bsq,
                            const float* __restrict__ gamma, const float* __restrict__ beta)
{
    constexpr int NT = COLS / 16;
    __shared__ unsigned short sBh[COLS * 128];   // 32KB (COLS=128) / 28KB (112)
    __shared__ unsigned short sBl[COLS * 128];
    __shared__ float scN[128], shN[128];

    int wv = threadIdx.x >> 6;
    int lane = threadIdx.x & 63;
    int r0 = blockIdx.x * 64 + wv * 16;
    int m = lane & 15;
    int quad = lane >> 4;
    int arow = r0 + m;
    int rc = (arow < NN) ? arow : NN - 1;    // clamp: pad rows computed but never stored

    // hoist A loads (issue before the barrier; complete during B staging)
    float4 av[8];
    u16x8 av16[4];
    if (BN_IN) {
        const unsigned short* pa = reinterpret_cast<const unsigned short*>(A)
                                 + (size_t)rc * 128 + quad * 8;
        #pragma unroll
        for (int ks = 0; ks < 4; ++ks)
            av16[ks] = *reinterpret_cast<const u16x8*>(pa + ks * 32);
    } else {
        const float* pa = reinterpret_cast<const float*>(A) + (size_t)rc * 128 + quad * 8;
        #pragma unroll
        for (int ks = 0; ks < 4; ++ks) {
            av[2 * ks]     = *reinterpret_cast<const float4*>(pa + ks * 32);
            av[2 * ks + 1] = *reinterpret_cast<const float4*>(pa + ks * 32 + 4);
        }
    }

    // stage B into LDS, swizzled: dest_byte = src_byte ^ ((row&7)<<4), row = byte>>8
    constexpr int CH = COLS * 128 * 2 / 16;      // 16B chunks: 2048 / 1792
    for (int i = threadIdx.x; i < CH; i += 256) {
        unsigned o = (unsigned)i * 16u;
        unsigned d = o ^ (((o >> 8) & 7u) << 4);
        *reinterpret_cast<uint4*>(reinterpret_cast<char*>(sBh) + d) =
            *reinterpret_cast<const uint4*>(reinterpret_cast<const char*>(Wth) + o);
        *reinterpret_cast<uint4*>(reinterpret_cast<char*>(sBl) + d) =
            *reinterpret_cast<const uint4*>(reinterpret_cast<const char*>(Wtl) + o);
    }
    if (BN_IN) {
        if (threadIdx.x < 128) {
            int k = threadIdx.x;
            float invn = 1.0f / (float)NN;
            float mean = bsum[k] * invn;
            float var  = bsq[k] * invn - mean * mean;
            float sc = gamma[k] * rsqrtf(var + 1e-5f);
            scN[k] = sc;
            shN[k] = beta[k] - mean * sc;
        }
    }
    __syncthreads();

    f32x4 acc[NT];
    #pragma unroll
    for (int t = 0; t < NT; ++t) acc[t] = f32x4{0.f, 0.f, 0.f, 0.f};

    unsigned swz = ((unsigned)(m & 7)) << 4;     // loop-invariant lane swizzle (16 % 8 == 0)

    #pragma unroll
    for (int ks = 0; ks < 4; ++ks) {
        float vv[8];
        if (BN_IN) {
            #pragma unroll
            for (int jj = 0; jj < 8; ++jj) vv[jj] = bf2f((unsigned short)av16[ks][jj]);
        } else {
            float4 v0 = av[2 * ks], v1 = av[2 * ks + 1];
            vv[0] = v0.x; vv[1] = v0.y; vv[2] = v0.z; vv[3] = v0.w;
            vv[4] = v1.x; vv[5] = v1.y; vv[6] = v1.z; vv[7] = v1.w;
        }
        int kb = ks * 32 + quad * 8;
        bf16x8 ah, al;
        #pragma unroll
        for (int jj = 0; jj < 8; ++jj) {
            float f = vv[jj];
            if (BN_IN) f = fmaxf(f * scN[kb + jj] + shN[kb + jj], 0.f);
            unsigned short hi = f2bf(f);
            ah[jj] = (short)hi;
            al[jj] = (short)f2bf(f - bf2f(hi));
        }
        #pragma unroll
        for (int t = 0; t < NT; ++t) {
            int c = t * 16 + m;
            unsigned b = ((unsigned)c * 256u + (unsigned)ks * 64u + (unsigned)quad * 16u) ^ swz;
            bf16x8 bh = *reinterpret_cast<const bf16x8*>(reinterpret_cast<const char*>(sBh) + b);
            bf16x8 bl = *reinterpret_cast<const bf16x8*>(reinterpret_cast<const char*>(sBl) + b);
            acc[t] = __builtin_amdgcn_mfma_f32_16x16x32_bf16(ah, bh, acc[t], 0, 0, 0);
            acc[t] = __builtin_amdgcn_mfma_f32_16x16x32_bf16(al, bh, acc[t], 0, 0, 0);
            acc[t] = __builtin_amdgcn_mfma_f32_16x16x32_bf16(ah, bl, acc[t], 0, 0, 0);
        }
    }

    // epilogue: bf16 store + fused attention dots (C/D: col=lane&15, row=quad*4+reg)
    float p[4] = {0.f, 0.f, 0.f, 0.f}, q[4] = {0.f, 0.f, 0.f, 0.f};
    #pragma unroll
    for (int t = 0; t < NT; ++t) {
        int c = t * 16 + m;
        float asv = a_src[c], adv = a_dst[c];
        #pragma unroll
        for (int rI = 0; rI < 4; ++rI) {
            float v = acc[t][rI];
            int row = r0 + quad * 4 + rI;
            if (row < NN) out[(size_t)row * COLS + c] = f2bf(v);
            p[rI] += v * asv;
            q[rI] += v * adv;
        }
    }
    #pragma unroll
    for (int rI = 0; rI < 4; ++rI) {
        #pragma unroll
        for (int off = 1; off <= 8; off <<= 1) {
            p[rI] += __shfl_xor(p[rI], off);
            q[rI] += __shfl_xor(q[rI], off);
        }
    }
    if (m == 0) {
        #pragma unroll
        for (int rI = 0; rI < 4; ++rI) {
            int row = r0 + quad * 4 + rI;
            if (row < NN) { als[row] = p[rI]; ald[row] = q[rI]; }
        }
    }
}

// ---------------- aggregate: QUARTER-PER-NODE, degree-sorted, inline logit+exp ------------
// 16 lanes own one node's full row. ordq[qid] = {w, beg, end} in one coalesced 16B load.
// Logit+exp computed inline from the packed record; output row stored bf16.
// 8 edges/pass = 8 record + 8 als + 8 xs loads in flight per lane; remainder masked.
template<int COLS, int LAYER>
__global__ void k_aggregate(const uint4* __restrict__ ordq, const uint2* __restrict__ pk,
                            const float* __restrict__ als, const float* __restrict__ ald,
                            const unsigned short* __restrict__ xs,
                            unsigned short* __restrict__ out,
                            float* __restrict__ psum, float* __restrict__ psq)
{
    __shared__ float sS[16 * 128], sQ[16 * 128];
    int ql = threadIdx.x & 15;
    int wq = threadIdx.x >> 4;               // 0..15 quarter slot within block
    int col = ql * 8;
    bool act = (col < COLS);
    int qid = blockIdx.x * 16 + wq;          // global quarter = node slot
    float bs[8] = {0.f,0.f,0.f,0.f,0.f,0.f,0.f,0.f};
    float bq[8] = {0.f,0.f,0.f,0.f,0.f,0.f,0.f,0.f};

    if (qid < NN) {
        uint4 o4 = ordq[qid];
        int w = (int)o4.x;
        int beg = (int)o4.y, end = (int)o4.z;
        float aldv = ald[w];
        float acc[8] = {0.f,0.f,0.f,0.f,0.f,0.f,0.f,0.f};
        float den = 0.f;
        int j = beg;
        for (; j + 8 <= end; j += 8) {
            uint2 r0 = pk[j],     r1 = pk[j + 1], r2 = pk[j + 2], r3 = pk[j + 3];
            uint2 r4 = pk[j + 4], r5 = pk[j + 5], r6 = pk[j + 6], r7 = pk[j + 7];
            float e0 = edge_ex<LAYER>(r0, aldv, als), e1 = edge_ex<LAYER>(r1, aldv, als);
            float e2 = edge_ex<LAYER>(r2, aldv, als), e3 = edge_ex<LAYER>(r3, aldv, als);
            float e4 = edge_ex<LAYER>(r4, aldv, als), e5 = edge_ex<LAYER>(r5, aldv, als);
            float e6 = edge_ex<LAYER>(r6, aldv, als), e7 = edge_ex<LAYER>(r7, aldv, als);
            den += ((e0 + e1) + (e2 + e3)) + ((e4 + e5) + (e6 + e7));
            if (act) {
                u16x8 u0 = *reinterpret_cast<const u16x8*>(xs + (size_t)(r0.x & 0xffffu) * COLS + col);
                u16x8 u1 = *reinterpret_cast<const u16x8*>(xs + (size_t)(r1.x & 0xffffu) * COLS + col);
                u16x8 u2 = *reinterpret_cast<const u16x8*>(xs + (size_t)(r2.x & 0xffffu) * COLS + col);
                u16x8 u3 = *reinterpret_cast<const u16x8*>(xs + (size_t)(r3.x & 0xffffu) * COLS + col);
                u16x8 u4 = *reinterpret_cast<const u16x8*>(xs + (size_t)(r4.x & 0xffffu) * COLS + col);
                u16x8 u5 = *reinterpret_cast<const u16x8*>(xs + (size_t)(r5.x & 0xffffu) * COLS + col);
                u16x8 u6 = *reinterpret_cast<const u16x8*>(xs + (size_t)(r6.x & 0xffffu) * COLS + col);
                u16x8 u7 = *reinterpret_cast<const u16x8*>(xs + (size_t)(r7.x & 0xffffu) * COLS + col);
                #pragma unroll
                for (int k = 0; k < 8; ++k)
                    acc[k] += (((e0 * bf2f(u0[k]) + e1 * bf2f(u1[k]))
                              + (e2 * bf2f(u2[k]) + e3 * bf2f(u3[k])))
                             + ((e4 * bf2f(u4[k]) + e5 * bf2f(u5[k]))
                              + (e6 * bf2f(u6[k]) + e7 * bf2f(u7[k]))));
            }
        }
        // remainder (1..7): one masked pass; invalid slots contribute ex=0
        if (j < end) {
            bool v1 = j + 1 < end, v2 = j + 2 < end, v3 = j + 3 < end;
            bool v4 = j + 4 < end, v5 = j + 5 < end, v6 = j + 6 < end;
            uint2 r0 = pk[j];
            uint2 r1 = v1 ? pk[j + 1] : uint2{0u, 0u};
            uint2 r2 = v2 ? pk[j + 2] : uint2{0u, 0u};
            uint2 r3 = v3 ? pk[j + 3] : uint2{0u, 0u};
            uint2 r4 = v4 ? pk[j + 4] : uint2{0u, 0u};
            uint2 r5 = v5 ? pk[j + 5] : uint2{0u, 0u};
            uint2 r6 = v6 ? pk[j + 6] : uint2{0u, 0u};
            float e0 = edge_ex<LAYER>(r0, aldv, als);
            float e1 = v1 ? edge_ex<LAYER>(r1, aldv, als) : 0.f;
            float e2 = v2 ? edge_ex<LAYER>(r2, aldv, als) : 0.f;
            float e3 = v3 ? edge_ex<LAYER>(r3, aldv, als) : 0.f;
            float e4 = v4 ? edge_ex<LAYER>(r4, aldv, als) : 0.f;
            float e5 = v5 ? edge_ex<LAYER>(r5, aldv, als) : 0.f;
            float e6 = v6 ? edge_ex<LAYER>(r6, aldv, als) : 0.f;
            den += ((e0 + e1) + (e2 + e3)) + ((e4 + e5) + e6);
            if (act) {
                u16x8 u0 = *reinterpret_cast<const u16x8*>(xs + (size_t)(r0.x & 0xffffu) * COLS + col);
                #pragma unroll
                for (int k = 0; k < 8; ++k) acc[k] += e0 * bf2f(u0[k]);
                if (v1) {
                    u16x8 u = *reinterpret_cast<const u16x8*>(xs + (size_t)(r1.x & 0xffffu) * COLS + col);
                    #pragma unroll
                    for (int k = 0; k < 8; ++k) acc[k] += e1 * bf2f(u[k]);
                }
                if (v2) {
                    u16x8 u = *reinterpret_cast<const u16x8*>(xs + (size_t)(r2.x & 0xffffu) * COLS + col);
                    #pragma unroll
                    for (int k = 0; k < 8; ++k) acc[k] += e2 * bf2f(u[k]);
                }
                if (v3) {
                    u16x8 u = *reinterpret_cast<const u16x8*>(xs + (size_t)(r3.x & 0xffffu) * COLS + col);
                    #pragma unroll
                    for (int k = 0; k < 8; ++k) acc[k] += e3 * bf2f(u[k]);
                }
                if (v4) {
                    u16x8 u = *reinterpret_cast<const u16x8*>(xs + (size_t)(r4.x & 0xffffu) * COLS + col);
                    #pragma unroll
                    for (int k = 0; k < 8; ++k) acc[k] += e4 * bf2f(u[k]);
                }
                if (v5) {
                    u16x8 u = *reinterpret_cast<const u16x8*>(xs + (size_t)(r5.x & 0xffffu) * COLS + col);
                    #pragma unroll
                    for (int k = 0; k < 8; ++k) acc[k] += e5 * bf2f(u[k]);
                }
                if (v6) {
                    u16x8 u = *reinterpret_cast<const u16x8*>(xs + (size_t)(r6.x & 0xffffu) * COLS + col);
                    #pragma unroll
                    for (int k = 0; k < 8; ++k) acc[k] += e6 * bf2f(u[k]);
                }
            }
        }
        float inv = (end > beg) ? 1.f / den : 0.f;
        if (act) {
            float o[8];
            u16x8 ob;
            #pragma unroll
            for (int k = 0; k < 8; ++k) {
                o[k] = acc[k] * inv;
                bs[k] += o[k];
                bq[k] += o[k] * o[k];
                ob[k] = f2bf(o[k]);
            }
            __builtin_nontemporal_store(ob,
                reinterpret_cast<u16x8*>(out + (size_t)w * COLS + col));
        }
    }
    // fold BN partials across the block's 16 quarters (once per kernel)
    #pragma unroll
    for (int k = 0; k < 8; ++k) {
        sS[wq * 128 + col + k] = act ? bs[k] : 0.f;
        sQ[wq * 128 + col + k] = act ? bq[k] : 0.f;
    }
    __syncthreads();
    int t = threadIdx.x;
    if (t < 128) {
        float s = 0.f, s2 = 0.f;
        #pragma unroll
        for (int r = 0; r < 16; ++r) { s += sS[r * 128 + t]; s2 += sQ[r * 128 + t]; }
        psum[(size_t)blockIdx.x * 128 + t] = s;
        psq [(size_t)blockIdx.x * 128 + t] = s2;
    }
}

// ---------------- BN stats stage 2: reduce AGG_NBLK partials (lightly-contended atomics) ----
__global__ void k_bn_stats2(const float* __restrict__ psum, const float* __restrict__ psq,
                            float* __restrict__ sums, float* __restrict__ sqs)
{
    int t = threadIdx.x;
    int c = t & 127;
    constexpr int ROWS = AGG_NBLK / 128;    // 25
    const float* sp = (t < 128) ? psum : psq;
    float s = 0.f;
    #pragma unroll 5
    for (int i = 0; i < ROWS; ++i)
        s += sp[(size_t)(blockIdx.x * ROWS + i) * 128 + c];
    unsafeAtomicAdd(((t < 128) ? sums : sqs) + c, s);
}

// ---------------- batchnorm apply (bf16 in -> fp32 d_out; 4 elems/thread) ----------------
template<int COLS>
__global__ void k_bn_apply(const unsigned short* __restrict__ in, float* __restrict__ out,
                           const float* __restrict__ sums, const float* __restrict__ sqs,
                           const float* __restrict__ gamma, const float* __restrict__ beta,
                           int n)
{
    int g = blockIdx.x * blockDim.x + threadIdx.x;       // group of 4 elements
    int base = g * 4;
    if (base >= n * COLS) return;
    int c0 = base % COLS;                                // COLS % 4 == 0 -> row-aligned
    ushort4 v = *reinterpret_cast<const ushort4*>(in + base);
    float invn = 1.0f / (float)n;
    float4 o;
    unsigned short vv[4] = {v.x, v.y, v.z, v.w};
    float oo[4];
    #pragma unroll
    for (int k = 0; k < 4; ++k) {
        int c = c0 + k;
        float mean = sums[c] * invn;
        float var  = sqs[c] * invn - mean * mean;        // biased, matches jnp var
        float sc = gamma[c] * rsqrtf(var + 1e-5f);
        float sh = beta[c] - mean * sc;
        oo[k] = bf2f(vv[k]) * sc + sh;
    }
    o.x = oo[0]; o.y = oo[1]; o.z = oo[2]; o.w = oo[3];
    *reinterpret_cast<float4*>(out + base) = o;
}

extern "C" void kernel_launch(void* const* d_in, const int* in_sizes, int n_in,
                              void* d_out, int out_size, void* d_ws, size_t ws_size,
                              hipStream_t stream)
{
    const float* x    = (const float*)d_in[0];
    const int*   eidx = (const int*)d_in[1];
    const float* eatt = (const float*)d_in[2];
    const float* W0   = (const float*)d_in[3];
    const float* as0  = (const float*)d_in[4];
    const float* ad0  = (const float*)d_in[5];
    const float* We0  = (const float*)d_in[6];
    const float* ae0  = (const float*)d_in[7];
    // d_in[8] = b0 : cancels through BN
    const float* W1   = (const float*)d_in[9];
    const float* as1  = (const float*)d_in[10];
    const float* ad1  = (const float*)d_in[11];
    const float* We1  = (const float*)d_in[12];
    const float* ae1  = (const float*)d_in[13];
    // d_in[14] = b1 : cancels through BN
    const float* bng  = (const float*)d_in[15];
    const float* bnb  = (const float*)d_in[16];
    const float* bnfg = (const float*)d_in[17];
    const float* bnfb = (const float*)d_in[18];

    const int N = NN, E = NE;
    const int* src = eidx;
    const int* dst = eidx + E;

    // ---- workspace layout (all scratch in ws; d_out written only by k_bn_apply) ----
    // Aliases (time-disjoint lifetimes):
    //   tmp (E*8B bucket records) lives inside xs1b (xs1b born at gemm112, tmp dead at fill_p2)
    //   out1 (N*112 bf16) lives inside h (h dead after layer-1 gemm consumes it)
    float* ws = (float*)d_ws;
    size_t off = 0;
    unsigned short* xs0b = (unsigned short*)(ws + off); off += (size_t)N * 64;   // N*128 bf16 (12.8MB)
    unsigned short* h = (unsigned short*)(ws + off);    off += (size_t)N * 64;   // N*128 bf16 (12.8MB)
    unsigned short* xs1b = (unsigned short*)(ws + off); off += (size_t)N * 56;   // N*112 bf16 (11.2MB)
    uint2* pk = (uint2*)(ws + off);     off += (size_t)E * 2;                    // 8B/edge (6.4MB)
    int*   rp   = (int*)(ws + off);     off += N + 2;
    uint4* ordq = (uint4*)(ws + off);   off += (size_t)N * 4;                    // {w,beg,end,0}
    int*   deg  = (int*)(ws + off);     off += N;
    float* als0 = ws + off;     off += N;
    float* ald0 = ws + off;     off += N;
    float* als1 = ws + off;     off += N;
    float* ald1 = ws + off;     off += N;
    float* stats = ws + off;    off += 512;
    float* ve = ws + off;       off += 16;
    int*   hist = (int*)(ws + off);     off += 64;
    int*   binCur = (int*)(ws + off);   off += 64;
    int*   bcur = (int*)(ws + off);     off += NBUCK;
    int*   partial = (int*)(ws + off);  off += SCAN_NBLK;
    float* psum = ws + off;     off += (size_t)AGG_NBLK * 128;
    float* psq  = ws + off;     off += (size_t)AGG_NBLK * 128;
    unsigned short* Wth0 = (unsigned short*)(ws + off); off += 128 * 64;         // 128x128 bf16
    unsigned short* Wtl0 = (unsigned short*)(ws + off); off += 128 * 64;
    unsigned short* Wth1 = (unsigned short*)(ws + off); off += 112 * 64;         // 112x128 bf16
    unsigned short* Wtl1 = (unsigned short*)(ws + off); off += 112 * 64;

    uint2* tmp = (uint2*)xs1b;          // E*8B = 6.4MB inside xs1b (11.2MB), time-disjoint
    unsigned short* out1 = h;           // N*112 bf16 (11.2MB <= 12.8MB), born after h dead

    float* sum0 = stats;
    float* sq0  = stats + 128;
    float* sum1 = stats + 256;
    float* sq1  = stats + 384;

    // ---- init (ws poisoned 0xAA before every call) ----
    k_init_cvt<<<(N + 255) / 256, 256, 0, stream>>>(deg, stats, hist, binCur,
                                                    We0, ae0, We1, ae1, ve,
                                                    W0, W1, Wth0, Wtl0, Wth1, Wtl1);

    // ---- CSR build: deg -> scan(+hist) -> scan3(+degree-sort) -> bucketed 2-phase fill ----
    k_deg<<<(E / 4 + 255) / 256, 256, 0, stream>>>(dst, deg, E);
    k_scan1<<<SCAN_NBLK, SCAN_B, 0, stream>>>(deg, partial, hist);
    k_scan3<<<SCAN_NBLK, SCAN_B, 0, stream>>>(deg, partial, rp, hist, binCur, ordq);
    k_binit<<<(NBUCK + 255) / 256, 256, 0, stream>>>(rp, bcur);
    k_fill_p1<<<(E / 4 + 255) / 256, 256, 0, stream>>>(src, dst, eatt, ve, bcur, tmp, E);
    k_fill_p2<<<NBUCK, 256, 0, stream>>>(rp, tmp, pk);

    // ---- layer 0: 128 -> 128 ----
    k_gemm_mfma<128, false><<<NPAD / 64, 256, 0, stream>>>(x, Wth0, Wtl0, xs0b,
                                                           as0, ad0, als0, ald0,
                                                           nullptr, nullptr, nullptr, nullptr);
    k_aggregate<128, 0><<<AGG_NBLK, 256, 0, stream>>>(ordq, pk, als0, ald0, xs0b, h, psum, psq);
    k_bn_stats2<<<128, 256, 0, stream>>>(psum, psq, sum0, sq0);

    // ---- layer 1: 128 -> 112 (BN0+ReLU fused into GEMM A-load, bf16 A) ----
    k_gemm_mfma<112, true><<<NPAD / 64, 256, 0, stream>>>(h, Wth1, Wtl1, xs1b,
                                                          as1, ad1, als1, ald1,
                                                          sum0, sq0, bng, bnb);
    k_aggregate<112, 1><<<AGG_NBLK, 256, 0, stream>>>(ordq, pk, als1, ald1, xs1b, out1, psum, psq);
    k_bn_stats2<<<128, 256, 0, stream>>>(psum, psq, sum1, sq1);
    k_bn_apply<112><<<(N * 112 / 4 + 255) / 256, 256, 0, stream>>>(out1, (float*)d_out, sum1, sq1, bnfg, bnfb, N);
}

// Round 10
// 312.316 us; speedup vs baseline: 1.4917x; 1.4917x over previous
//
#include <hip/hip_runtime.h>
#include <math.h>

// GAT 2-layer: N=50000 nodes, E=800000 edges, heads=1
// dims: 128 -> 128 (BN+ReLU) -> 112 (BN)
#define NN 50000
#define NPAD 50048               // 782 * 64, MFMA row tiles
#define NE 800000
#define SCAN_B 256
#define SCAN_NBLK ((NN + SCAN_B - 1) / SCAN_B)   // 196
#define AGG_NBLK 3200            // 3200 blocks * 16 quarters = 51200 slots >= NN

typedef __attribute__((ext_vector_type(8))) short bf16x8;           // MFMA A/B frag
typedef __attribute__((ext_vector_type(4))) float f32x4;            // MFMA C/D frag
typedef __attribute__((ext_vector_type(8))) unsigned short u16x8;   // 16B gather / bf16 store

__device__ __forceinline__ unsigned short f2bf(float x) {
    unsigned u = __float_as_uint(x);
    u += 0x7fffu + ((u >> 16) & 1);              // round-to-nearest-even
    return (unsigned short)(u >> 16);
}
__device__ __forceinline__ float bf2f(unsigned short h) {
    return __uint_as_float(((unsigned)h) << 16);
}

// per-edge logit+exp from a packed record, computed INSIDE the aggregate (layer-select
// by template). als[src] is a 16-lane broadcast gather against a 200KB L2-resident array.
template<int LAYER>
__device__ __forceinline__ float edge_ex(uint2 r, float aldv, const float* __restrict__ als)
{
    float ae = bf2f((unsigned short)(LAYER ? (r.y & 0xffffu) : (r.x >> 16)));
    float a = als[r.x & 0xffffu] + aldv + ae;
    a = a > 0.f ? a : 0.2f * a;
    return __expf(a);
}

// ---------------- init: deg/stats/hist zero + ve fold + W split-transpose ----------------
// ve[0..7] = We0 @ a_edge0 ; ve[8..15] = We1 @ a_edge1   (heads=1 folding)
__global__ void k_init_cvt(int* __restrict__ deg, float* __restrict__ stats,
                           int* __restrict__ hist, int* __restrict__ binCur,
                           const float* __restrict__ We0, const float* __restrict__ ae0,
                           const float* __restrict__ We1, const float* __restrict__ ae1,
                           float* __restrict__ ve,
                           const float* __restrict__ W0, const float* __restrict__ W1,
                           unsigned short* __restrict__ Wth0, unsigned short* __restrict__ Wtl0,
                           unsigned short* __restrict__ Wth1, unsigned short* __restrict__ Wtl1)
{
    int idx = blockIdx.x * 256 + threadIdx.x;
    if (idx < NN) deg[idx] = 0;
    if (idx < 512) stats[idx] = 0.f;
    if (idx < 64) { hist[idx] = 0; binCur[idx] = 0; }
    if (idx < 128 * 128) {
        int k = idx / 128, c = idx % 128;
        float v = W0[idx];
        unsigned short hi = f2bf(v);
        Wth0[c * 128 + k] = hi;
        Wtl0[c * 128 + k] = f2bf(v - bf2f(hi));
    } else if (idx < 128 * 128 + 128 * 112) {
        int i2 = idx - 128 * 128;
        int k = i2 / 112, c = i2 % 112;
        float v = W1[i2];
        unsigned short hi = f2bf(v);
        Wth1[c * 128 + k] = hi;
        Wtl1[c * 128 + k] = f2bf(v - bf2f(hi));
    }
    if (blockIdx.x == gridDim.x - 1) {
        int j = threadIdx.x;
        if (j < 8) {
            float s = 0.f;
            for (int c = 0; c < 128; ++c) s += We0[j * 128 + c] * ae0[c];
            ve[j] = s;
        } else if (j < 16) {
            int jj = j - 8;
            float s = 0.f;
            for (int c = 0; c < 112; ++c) s += We1[jj * 112 + c] * ae1[c];
            ve[8 + jj] = s;
        }
    }
}

// ---------------- CSR build ----------------
// rank[e] = old count of dst (atomic return). 50K spread-out counters = ~16 ops/counter,
// benign contention (round-9's 1K hot cursors at 781 ops/counter cost 166us -- never again).
__global__ void k_deg(const int* __restrict__ dst, int* __restrict__ deg,
                      int* __restrict__ rank, int E_)
{
    int i = blockIdx.x * blockDim.x + threadIdx.x;
    int e = i * 2;
    if (e + 2 <= E_) {
        int2 dd = *reinterpret_cast<const int2*>(dst + e);
        int2 rr;
        rr.x = atomicAdd(&deg[dd.x], 1);
        rr.y = atomicAdd(&deg[dd.y], 1);
        *reinterpret_cast<int2*>(rank + e) = rr;
    } else if (e < E_) {
        rank[e] = atomicAdd(&deg[dst[e]], 1);
    }
}

// block reduce for rp-scan partials + 64-bin degree histogram (LDS-aggregated).
// bin = 63 - min(deg,63): ascending bin == DESCENDING degree for the balance sort.
__global__ void k_scan1(const int* __restrict__ deg, int* __restrict__ partial,
                        int* __restrict__ hist)
{
    __shared__ int sm[SCAN_B];
    __shared__ int lh[64];
    int t = threadIdx.x;
    if (t < 64) lh[t] = 0;
    int idx = blockIdx.x * SCAN_B + t;
    int d = (idx < NN) ? deg[idx] : 0;
    sm[t] = d;
    __syncthreads();
    if (idx < NN) atomicAdd(&lh[63 - (d < 63 ? d : 63)], 1);
    #pragma unroll
    for (int off = SCAN_B / 2; off > 0; off >>= 1) {
        if (t < off) sm[t] += sm[t + off];
        __syncthreads();
    }
    if (t == 0) partial[blockIdx.x] = sm[0];
    if (t < 64 && lh[t]) atomicAdd(&hist[t], lh[t]);
}

// fused stage 2+3: per-block prefix over partials, local scan -> rp;
// then degree-sort scatter of {node, beg, end} uint4 records into ordq[].
__global__ void k_scan3(const int* __restrict__ deg, const int* __restrict__ partial,
                        int* __restrict__ rp, const int* __restrict__ hist,
                        int* __restrict__ binCur, uint4* __restrict__ ordq)
{
    __shared__ int sm[SCAN_B];
    __shared__ int pbase;
    __shared__ int lh[64], lrsv[64], lstart[64];
    int t = threadIdx.x;
    int pv = (t < SCAN_NBLK && t < blockIdx.x) ? partial[t] : 0;
    sm[t] = pv;
    __syncthreads();
    #pragma unroll
    for (int off = SCAN_B / 2; off > 0; off >>= 1) {
        if (t < off) sm[t] += sm[t + off];
        __syncthreads();
    }
    if (t == 0) pbase = sm[0];
    __syncthreads();
    int idx = blockIdx.x * SCAN_B + t;
    int v = (idx < NN) ? deg[idx] : 0;
    sm[t] = v;
    __syncthreads();
    #pragma unroll
    for (int off = 1; off < SCAN_B; off <<= 1) {
        int u = (t >= off) ? sm[t - off] : 0;
        __syncthreads();
        sm[t] += u;
        __syncthreads();
    }
    int excl = pbase + ((t == 0) ? 0 : sm[t - 1]);
    if (idx < NN) rp[idx] = excl;
    if (idx == NN - 1) rp[NN] = excl + v;

    // ---- degree-sort scatter of {node, beg, end} ----
    if (t < 64) lh[t] = 0;
    __syncthreads();
    int b = 0, lr = 0;
    if (idx < NN) {
        b = 63 - (v < 63 ? v : 63);
        lr = atomicAdd(&lh[b], 1);
    }
    __syncthreads();
    if (t < 64) {
        lrsv[t] = lh[t] ? atomicAdd(&binCur[t], lh[t]) : 0;
        int s = 0;
        for (int i = 0; i < t; ++i) s += hist[i];
        lstart[t] = s;
    }
    __syncthreads();
    if (idx < NN) {
        uint4 rec;
        rec.x = (unsigned)idx;
        rec.y = (unsigned)excl;
        rec.z = (unsigned)(excl + v);
        rec.w = 0u;
        ordq[lstart[b] + lrsv[b] + lr] = rec;
    }
}

// ---------------- edge pack: 8B records {src16|a0_bf16, a1_bf16}, CSR order ----------------
// Pure pack: no als/ald gathers, no exp (logits computed inline in the aggregates).
// 4 edges/thread: int4 index loads, 128B of eatt, 4 independent scatters in flight.
// pos = rp[dst] + rank (precomputed) -> scatter store is fire-and-forget, no atomic.
__global__ void k_csr_fill(const int* __restrict__ src, const int* __restrict__ dst,
                           const float* __restrict__ eatt, const float* __restrict__ ve,
                           const int* __restrict__ rp, const int* __restrict__ rank,
                           uint2* __restrict__ pk, int E_)
{
    int i = blockIdx.x * blockDim.x + threadIdx.x;
    int e = i * 4;
    if (e >= E_) return;
    int4 ss = *reinterpret_cast<const int4*>(src + e);
    int4 dd = *reinterpret_cast<const int4*>(dst + e);
    int4 rr = *reinterpret_cast<const int4*>(rank + e);
    const float4* ea = reinterpret_cast<const float4*>(eatt + (size_t)e * 8);

    float v0 = ve[0], v1 = ve[1], v2 = ve[2], v3 = ve[3];
    float v4 = ve[4], v5 = ve[5], v6 = ve[6], v7 = ve[7];
    float w0 = ve[8], w1 = ve[9], w2 = ve[10], w3 = ve[11];
    float w4 = ve[12], w5 = ve[13], w6 = ve[14], w7 = ve[15];

    int s4[4] = {ss.x, ss.y, ss.z, ss.w};
    int d4[4] = {dd.x, dd.y, dd.z, dd.w};
    int r4[4] = {rr.x, rr.y, rr.z, rr.w};
    #pragma unroll
    for (int k = 0; k < 4; ++k) {
        float4 u0 = ea[2 * k], u1 = ea[2 * k + 1];
        float a0 = u0.x * v0 + u0.y * v1 + u0.z * v2 + u0.w * v3
                 + u1.x * v4 + u1.y * v5 + u1.z * v6 + u1.w * v7;
        float a1 = u0.x * w0 + u0.y * w1 + u0.z * w2 + u0.w * w3
                 + u1.x * w4 + u1.y * w5 + u1.z * w6 + u1.w * w7;
        int pos = rp[d4[k]] + r4[k];
        uint2 rec;
        rec.x = (unsigned)s4[k] | ((unsigned)f2bf(a0) << 16);
        rec.y = (unsigned)f2bf(a1);
        pk[pos] = rec;
    }
}

// ---------------- MFMA GEMM: one wave = 16 rows x COLS, bf16x3 split precision ----------------
// B (Wth+Wtl) staged in LDS with XOR swizzle; A loads hoisted before the staging barrier.
// BN_IN=false: A is fp32 (input x). BN_IN=true: A is bf16 (h), BN0+ReLU fused on load.
template<int COLS, bool BN_IN>
__launch_bounds__(256, 2)
__global__ void k_gemm_mfma(const void* __restrict__ A,
                            const unsigned short* __restrict__ Wth,
                            const unsigned short* __restrict__ Wtl,
                            unsigned short* __restrict__ out,
                            const float* __restrict__ a_src, const float* __restrict__ a_dst,
                            float* __restrict__ als, float* __restrict__ ald,
                            const float* __restrict__ bsum, const float* __restrict__ bsq,
                            const float* __restrict__ gamma, const float* __restrict__ beta)
{
    constexpr int NT = COLS / 16;
    __shared__ unsigned short sBh[COLS * 128];   // 32KB (COLS=128) / 28KB (112)
    __shared__ unsigned short sBl[COLS * 128];
    __shared__ float scN[128], shN[128];

    int wv = threadIdx.x >> 6;
    int lane = threadIdx.x & 63;
    int r0 = blockIdx.x * 64 + wv * 16;
    int m = lane & 15;
    int quad = lane >> 4;
    int arow = r0 + m;
    int rc = (arow < NN) ? arow : NN - 1;    // clamp: pad rows computed but never stored

    // hoist A loads (issue before the barrier; complete during B staging)
    float4 av[8];
    u16x8 av16[4];
    if (BN_IN) {
        const unsigned short* pa = reinterpret_cast<const unsigned short*>(A)
                                 + (size_t)rc * 128 + quad * 8;
        #pragma unroll
        for (int ks = 0; ks < 4; ++ks)
            av16[ks] = *reinterpret_cast<const u16x8*>(pa + ks * 32);
    } else {
        const float* pa = reinterpret_cast<const float*>(A) + (size_t)rc * 128 + quad * 8;
        #pragma unroll
        for (int ks = 0; ks < 4; ++ks) {
            av[2 * ks]     = *reinterpret_cast<const float4*>(pa + ks * 32);
            av[2 * ks + 1] = *reinterpret_cast<const float4*>(pa + ks * 32 + 4);
        }
    }

    // stage B into LDS, swizzled: dest_byte = src_byte ^ ((row&7)<<4), row = byte>>8
    constexpr int CH = COLS * 128 * 2 / 16;      // 16B chunks: 2048 / 1792
    for (int i = threadIdx.x; i < CH; i += 256) {
        unsigned o = (unsigned)i * 16u;
        unsigned d = o ^ (((o >> 8) & 7u) << 4);
        *reinterpret_cast<uint4*>(reinterpret_cast<char*>(sBh) + d) =
            *reinterpret_cast<const uint4*>(reinterpret_cast<const char*>(Wth) + o);
        *reinterpret_cast<uint4*>(reinterpret_cast<char*>(sBl) + d) =
            *reinterpret_cast<const uint4*>(reinterpret_cast<const char*>(Wtl) + o);
    }
    if (BN_IN) {
        if (threadIdx.x < 128) {
            int k = threadIdx.x;
            float invn = 1.0f / (float)NN;
            float mean = bsum[k] * invn;
            float var  = bsq[k] * invn - mean * mean;
            float sc = gamma[k] * rsqrtf(var + 1e-5f);
            scN[k] = sc;
            shN[k] = beta[k] - mean * sc;
        }
    }
    __syncthreads();

    f32x4 acc[NT];
    #pragma unroll
    for (int t = 0; t < NT; ++t) acc[t] = f32x4{0.f, 0.f, 0.f, 0.f};

    unsigned swz = ((unsigned)(m & 7)) << 4;     // loop-invariant lane swizzle (16 % 8 == 0)

    #pragma unroll
    for (int ks = 0; ks < 4; ++ks) {
        float vv[8];
        if (BN_IN) {
            #pragma unroll
            for (int jj = 0; jj < 8; ++jj) vv[jj] = bf2f((unsigned short)av16[ks][jj]);
        } else {
            float4 v0 = av[2 * ks], v1 = av[2 * ks + 1];
            vv[0] = v0.x; vv[1] = v0.y; vv[2] = v0.z; vv[3] = v0.w;
            vv[4] = v1.x; vv[5] = v1.y; vv[6] = v1.z; vv[7] = v1.w;
        }
        int kb = ks * 32 + quad * 8;
        bf16x8 ah, al;
        #pragma unroll
        for (int jj = 0; jj < 8; ++jj) {
            float f = vv[jj];
            if (BN_IN) f = fmaxf(f * scN[kb + jj] + shN[kb + jj], 0.f);
            unsigned short hi = f2bf(f);
            ah[jj] = (short)hi;
            al[jj] = (short)f2bf(f - bf2f(hi));
        }
        #pragma unroll
        for (int t = 0; t < NT; ++t) {
            int c = t * 16 + m;
            unsigned b = ((unsigned)c * 256u + (unsigned)ks * 64u + (unsigned)quad * 16u) ^ swz;
            bf16x8 bh = *reinterpret_cast<const bf16x8*>(reinterpret_cast<const char*>(sBh) + b);
            bf16x8 bl = *reinterpret_cast<const bf16x8*>(reinterpret_cast<const char*>(sBl) + b);
            acc[t] = __builtin_amdgcn_mfma_f32_16x16x32_bf16(ah, bh, acc[t], 0, 0, 0);
            acc[t] = __builtin_amdgcn_mfma_f32_16x16x32_bf16(al, bh, acc[t], 0, 0, 0);
            acc[t] = __builtin_amdgcn_mfma_f32_16x16x32_bf16(ah, bl, acc[t], 0, 0, 0);
        }
    }

    // epilogue: bf16 store + fused attention dots (C/D: col=lane&15, row=quad*4+reg)
    float p[4] = {0.f, 0.f, 0.f, 0.f}, q[4] = {0.f, 0.f, 0.f, 0.f};
    #pragma unroll
    for (int t = 0; t < NT; ++t) {
        int c = t * 16 + m;
        float asv = a_src[c], adv = a_dst[c];
        #pragma unroll
        for (int rI = 0; rI < 4; ++rI) {
            float v = acc[t][rI];
            int row = r0 + quad * 4 + rI;
            if (row < NN) out[(size_t)row * COLS + c] = f2bf(v);
            p[rI] += v * asv;
            q[rI] += v * adv;
        }
    }
    #pragma unroll
    for (int rI = 0; rI < 4; ++rI) {
        #pragma unroll
        for (int off = 1; off <= 8; off <<= 1) {
            p[rI] += __shfl_xor(p[rI], off);
            q[rI] += __shfl_xor(q[rI], off);
        }
    }
    if (m == 0) {
        #pragma unroll
        for (int rI = 0; rI < 4; ++rI) {
            int row = r0 + quad * 4 + rI;
            if (row < NN) { als[row] = p[rI]; ald[row] = q[rI]; }
        }
    }
}

// ---------------- aggregate: QUARTER-PER-NODE, degree-sorted, inline logit+exp ------------
// 16 lanes own one node's full row. ordq[qid] = {w, beg, end} in one coalesced 16B load.
// Logit+exp computed inline from the packed record; output row stored bf16.
// 8 edges/pass = 8 record + 8 als + 8 xs loads in flight per lane; remainder masked.
template<int COLS, int LAYER>
__global__ void k_aggregate(const uint4* __restrict__ ordq, const uint2* __restrict__ pk,
                            const float* __restrict__ als, const float* __restrict__ ald,
                            const unsigned short* __restrict__ xs,
                            unsigned short* __restrict__ out,
                            float* __restrict__ psum, float* __restrict__ psq)
{
    __shared__ float sS[16 * 128], sQ[16 * 128];
    int ql = threadIdx.x & 15;
    int wq = threadIdx.x >> 4;               // 0..15 quarter slot within block
    int col = ql * 8;
    bool act = (col < COLS);
    int qid = blockIdx.x * 16 + wq;          // global quarter = node slot
    float bs[8] = {0.f,0.f,0.f,0.f,0.f,0.f,0.f,0.f};
    float bq[8] = {0.f,0.f,0.f,0.f,0.f,0.f,0.f,0.f};

    if (qid < NN) {
        uint4 o4 = ordq[qid];
        int w = (int)o4.x;
        int beg = (int)o4.y, end = (int)o4.z;
        float aldv = ald[w];
        float acc[8] = {0.f,0.f,0.f,0.f,0.f,0.f,0.f,0.f};
        float den = 0.f;
        int j = beg;
        for (; j + 8 <= end; j += 8) {
            uint2 r0 = pk[j],     r1 = pk[j + 1], r2 = pk[j + 2], r3 = pk[j + 3];
            uint2 r4 = pk[j + 4], r5 = pk[j + 5], r6 = pk[j + 6], r7 = pk[j + 7];
            float e0 = edge_ex<LAYER>(r0, aldv, als), e1 = edge_ex<LAYER>(r1, aldv, als);
            float e2 = edge_ex<LAYER>(r2, aldv, als), e3 = edge_ex<LAYER>(r3, aldv, als);
            float e4 = edge_ex<LAYER>(r4, aldv, als), e5 = edge_ex<LAYER>(r5, aldv, als);
            float e6 = edge_ex<LAYER>(r6, aldv, als), e7 = edge_ex<LAYER>(r7, aldv, als);
            den += ((e0 + e1) + (e2 + e3)) + ((e4 + e5) + (e6 + e7));
            if (act) {
                u16x8 u0 = *reinterpret_cast<const u16x8*>(xs + (size_t)(r0.x & 0xffffu) * COLS + col);
                u16x8 u1 = *reinterpret_cast<const u16x8*>(xs + (size_t)(r1.x & 0xffffu) * COLS + col);
                u16x8 u2 = *reinterpret_cast<const u16x8*>(xs + (size_t)(r2.x & 0xffffu) * COLS + col);
                u16x8 u3 = *reinterpret_cast<const u16x8*>(xs + (size_t)(r3.x & 0xffffu) * COLS + col);
                u16x8 u4 = *reinterpret_cast<const u16x8*>(xs + (size_t)(r4.x & 0xffffu) * COLS + col);
                u16x8 u5 = *reinterpret_cast<const u16x8*>(xs + (size_t)(r5.x & 0xffffu) * COLS + col);
                u16x8 u6 = *reinterpret_cast<const u16x8*>(xs + (size_t)(r6.x & 0xffffu) * COLS + col);
                u16x8 u7 = *reinterpret_cast<const u16x8*>(xs + (size_t)(r7.x & 0xffffu) * COLS + col);
                #pragma unroll
                for (int k = 0; k < 8; ++k)
                    acc[k] += (((e0 * bf2f(u0[k]) + e1 * bf2f(u1[k]))
                              + (e2 * bf2f(u2[k]) + e3 * bf2f(u3[k])))
                             + ((e4 * bf2f(u4[k]) + e5 * bf2f(u5[k]))
                              + (e6 * bf2f(u6[k]) + e7 * bf2f(u7[k]))));
            }
        }
        // remainder (1..7): one masked pass; invalid slots contribute ex=0
        if (j < end) {
            bool v1 = j + 1 < end, v2 = j + 2 < end, v3 = j + 3 < end;
            bool v4 = j + 4 < end, v5 = j + 5 < end, v6 = j + 6 < end;
            uint2 r0 = pk[j];
            uint2 r1 = v1 ? pk[j + 1] : uint2{0u, 0u};
            uint2 r2 = v2 ? pk[j + 2] : uint2{0u, 0u};
            uint2 r3 = v3 ? pk[j + 3] : uint2{0u, 0u};
            uint2 r4 = v4 ? pk[j + 4] : uint2{0u, 0u};
            uint2 r5 = v5 ? pk[j + 5] : uint2{0u, 0u};
            uint2 r6 = v6 ? pk[j + 6] : uint2{0u, 0u};
            float e0 = edge_ex<LAYER>(r0, aldv, als);
            float e1 = v1 ? edge_ex<LAYER>(r1, aldv, als) : 0.f;
            float e2 = v2 ? edge_ex<LAYER>(r2, aldv, als) : 0.f;
            float e3 = v3 ? edge_ex<LAYER>(r3, aldv, als) : 0.f;
            float e4 = v4 ? edge_ex<LAYER>(r4, aldv, als) : 0.f;
            float e5 = v5 ? edge_ex<LAYER>(r5, aldv, als) : 0.f;
            float e6 = v6 ? edge_ex<LAYER>(r6, aldv, als) : 0.f;
            den += ((e0 + e1) + (e2 + e3)) + ((e4 + e5) + e6);
            if (act) {
                u16x8 u0 = *reinterpret_cast<const u16x8*>(xs + (size_t)(r0.x & 0xffffu) * COLS + col);
                #pragma unroll
                for (int k = 0; k < 8; ++k) acc[k] += e0 * bf2f(u0[k]);
                if (v1) {
                    u16x8 u = *reinterpret_cast<const u16x8*>(xs + (size_t)(r1.x & 0xffffu) * COLS + col);
                    #pragma unroll
                    for (int k = 0; k < 8; ++k) acc[k] += e1 * bf2f(u[k]);
                }
                if (v2) {
                    u16x8 u = *reinterpret_cast<const u16x8*>(xs + (size_t)(r2.x & 0xffffu) * COLS + col);
                    #pragma unroll
                    for (int k = 0; k < 8; ++k) acc[k] += e2 * bf2f(u[k]);
                }
                if (v3) {
                    u16x8 u = *reinterpret_cast<const u16x8*>(xs + (size_t)(r3.x & 0xffffu) * COLS + col);
                    #pragma unroll
                    for (int k = 0; k < 8; ++k) acc[k] += e3 * bf2f(u[k]);
                }
                if (v4) {
                    u16x8 u = *reinterpret_cast<const u16x8*>(xs + (size_t)(r4.x & 0xffffu) * COLS + col);
                    #pragma unroll
                    for (int k = 0; k < 8; ++k) acc[k] += e4 * bf2f(u[k]);
                }
                if (v5) {
                    u16x8 u = *reinterpret_cast<const u16x8*>(xs + (size_t)(r5.x & 0xffffu) * COLS + col);
                    #pragma unroll
                    for (int k = 0; k < 8; ++k) acc[k] += e5 * bf2f(u[k]);
                }
                if (v6) {
                    u16x8 u = *reinterpret_cast<const u16x8*>(xs + (size_t)(r6.x & 0xffffu) * COLS + col);
                    #pragma unroll
                    for (int k = 0; k < 8; ++k) acc[k] += e6 * bf2f(u[k]);
                }
            }
        }
        float inv = (end > beg) ? 1.f / den : 0.f;
        if (act) {
            float o[8];
            u16x8 ob;
            #pragma unroll
            for (int k = 0; k < 8; ++k) {
                o[k] = acc[k] * inv;
                bs[k] += o[k];
                bq[k] += o[k] * o[k];
                ob[k] = f2bf(o[k]);
            }
            __builtin_nontemporal_store(ob,
                reinterpret_cast<u16x8*>(out + (size_t)w * COLS + col));
        }
    }
    // fold BN partials across the block's 16 quarters (once per kernel)
    #pragma unroll
    for (int k = 0; k < 8; ++k) {
        sS[wq * 128 + col + k] = act ? bs[k] : 0.f;
        sQ[wq * 128 + col + k] = act ? bq[k] : 0.f;
    }
    __syncthreads();
    int t = threadIdx.x;
    if (t < 128) {
        float s = 0.f, s2 = 0.f;
        #pragma unroll
        for (int r = 0; r < 16; ++r) { s += sS[r * 128 + t]; s2 += sQ[r * 128 + t]; }
        psum[(size_t)blockIdx.x * 128 + t] = s;
        psq [(size_t)blockIdx.x * 128 + t] = s2;
    }
}

// ---------------- BN stats stage 2: reduce AGG_NBLK partials (lightly-contended atomics) ----
__global__ void k_bn_stats2(const float* __restrict__ psum, const float* __restrict__ psq,
                            float* __restrict__ sums, float* __restrict__ sqs)
{
    int t = threadIdx.x;
    int c = t & 127;
    constexpr int ROWS = AGG_NBLK / 128;    // 25
    const float* sp = (t < 128) ? psum : psq;
    float s = 0.f;
    #pragma unroll 5
    for (int i = 0; i < ROWS; ++i)
        s += sp[(size_t)(blockIdx.x * ROWS + i) * 128 + c];
    unsafeAtomicAdd(((t < 128) ? sums : sqs) + c, s);
}

// ---------------- batchnorm apply (bf16 in -> fp32 d_out; 4 elems/thread) ----------------
template<int COLS>
__global__ void k_bn_apply(const unsigned short* __restrict__ in, float* __restrict__ out,
                           const float* __restrict__ sums, const float* __restrict__ sqs,
                           const float* __restrict__ gamma, const float* __restrict__ beta,
                           int n)
{
    int g = blockIdx.x * blockDim.x + threadIdx.x;       // group of 4 elements
    int base = g * 4;
    if (base >= n * COLS) return;
    int c0 = base % COLS;                                // COLS % 4 == 0 -> row-aligned
    ushort4 v = *reinterpret_cast<const ushort4*>(in + base);
    float invn = 1.0f / (float)n;
    float4 o;
    unsigned short vv[4] = {v.x, v.y, v.z, v.w};
    float oo[4];
    #pragma unroll
    for (int k = 0; k < 4; ++k) {
        int c = c0 + k;
        float mean = sums[c] * invn;
        float var  = sqs[c] * invn - mean * mean;        // biased, matches jnp var
        float sc = gamma[c] * rsqrtf(var + 1e-5f);
        float sh = beta[c] - mean * sc;
        oo[k] = bf2f(vv[k]) * sc + sh;
    }
    o.x = oo[0]; o.y = oo[1]; o.z = oo[2]; o.w = oo[3];
    *reinterpret_cast<float4*>(out + base) = o;
}

extern "C" void kernel_launch(void* const* d_in, const int* in_sizes, int n_in,
                              void* d_out, int out_size, void* d_ws, size_t ws_size,
                              hipStream_t stream)
{
    const float* x    = (const float*)d_in[0];
    const int*   eidx = (const int*)d_in[1];
    const float* eatt = (const float*)d_in[2];
    const float* W0   = (const float*)d_in[3];
    const float* as0  = (const float*)d_in[4];
    const float* ad0  = (const float*)d_in[5];
    const float* We0  = (const float*)d_in[6];
    const float* ae0  = (const float*)d_in[7];
    // d_in[8] = b0 : cancels through BN
    const float* W1   = (const float*)d_in[9];
    const float* as1  = (const float*)d_in[10];
    const float* ad1  = (const float*)d_in[11];
    const float* We1  = (const float*)d_in[12];
    const float* ae1  = (const float*)d_in[13];
    // d_in[14] = b1 : cancels through BN
    const float* bng  = (const float*)d_in[15];
    const float* bnb  = (const float*)d_in[16];
    const float* bnfg = (const float*)d_in[17];
    const float* bnfb = (const float*)d_in[18];

    const int N = NN, E = NE;
    const int* src = eidx;
    const int* dst = eidx + E;

    // ---- workspace layout (all scratch in ws; d_out written only by k_bn_apply) ----
    // Aliases (time-disjoint lifetimes):
    //   rank, deg live inside h (dead before k_aggregate<128> writes h)
    //   out1 (N*112 bf16) lives inside h (h dead after layer-1 gemm consumes it)
    float* ws = (float*)d_ws;
    size_t off = 0;
    unsigned short* xs0b = (unsigned short*)(ws + off); off += (size_t)N * 64;   // N*128 bf16 (12.8MB)
    unsigned short* h = (unsigned short*)(ws + off);    off += (size_t)N * 64;   // N*128 bf16 (12.8MB)
    unsigned short* xs1b = (unsigned short*)(ws + off); off += (size_t)N * 56;   // N*112 bf16 (11.2MB)
    uint2* pk = (uint2*)(ws + off);     off += (size_t)E * 2;                    // 8B/edge (6.4MB)
    int*   rp   = (int*)(ws + off);     off += N + 2;
    uint4* ordq = (uint4*)(ws + off);   off += (size_t)N * 4;                    // {w,beg,end,0}
    float* als0 = ws + off;     off += N;
    float* ald0 = ws + off;     off += N;
    float* als1 = ws + off;     off += N;
    float* ald1 = ws + off;     off += N;
    float* stats = ws + off;    off += 512;
    float* ve = ws + off;       off += 16;
    int*   hist = (int*)(ws + off);     off += 64;
    int*   binCur = (int*)(ws + off);   off += 64;
    int*   partial = (int*)(ws + off);  off += SCAN_NBLK;
    float* psum = ws + off;     off += (size_t)AGG_NBLK * 128;
    float* psq  = ws + off;     off += (size_t)AGG_NBLK * 128;
    unsigned short* Wth0 = (unsigned short*)(ws + off); off += 128 * 64;         // 128x128 bf16
    unsigned short* Wtl0 = (unsigned short*)(ws + off); off += 128 * 64;
    unsigned short* Wth1 = (unsigned short*)(ws + off); off += 112 * 64;         // 112x128 bf16
    unsigned short* Wtl1 = (unsigned short*)(ws + off); off += 112 * 64;

    int*   rank = (int*)h;              // E ints in h bytes [0 : 3.2MB)  (dead before h written)
    int*   deg  = ((int*)h) + 800000;   // N ints right after rank
    unsigned short* out1 = h;           // N*112 bf16 (11.2MB <= 12.8MB), born after h dead

    float* sum0 = stats;
    float* sq0  = stats + 128;
    float* sum1 = stats + 256;
    float* sq1  = stats + 384;

    // ---- init (ws poisoned 0xAA before every call) ----
    k_init_cvt<<<(N + 255) / 256, 256, 0, stream>>>(deg, stats, hist, binCur,
                                                    We0, ae0, We1, ae1, ve,
                                                    W0, W1, Wth0, Wtl0, Wth1, Wtl1);

    // ---- CSR build: deg(+rank) -> scan(+hist) -> scan3(+degree-sort) -> direct fill ----
    k_deg<<<(E / 2 + 255) / 256, 256, 0, stream>>>(dst, deg, rank, E);
    k_scan1<<<SCAN_NBLK, SCAN_B, 0, stream>>>(deg, partial, hist);
    k_scan3<<<SCAN_NBLK, SCAN_B, 0, stream>>>(deg, partial, rp, hist, binCur, ordq);
    k_csr_fill<<<(E / 4 + 255) / 256, 256, 0, stream>>>(src, dst, eatt, ve, rp, rank, pk, E);

    // ---- layer 0: 128 -> 128 ----
    k_gemm_mfma<128, false><<<NPAD / 64, 256, 0, stream>>>(x, Wth0, Wtl0, xs0b,
                                                           as0, ad0, als0, ald0,
                                                           nullptr, nullptr, nullptr, nullptr);
    k_aggregate<128, 0><<<AGG_NBLK, 256, 0, stream>>>(ordq, pk, als0, ald0, xs0b, h, psum, psq);
    k_bn_stats2<<<128, 256, 0, stream>>>(psum, psq, sum0, sq0);

    // ---- layer 1: 128 -> 112 (BN0+ReLU fused into GEMM A-load, bf16 A) ----
    k_gemm_mfma<112, true><<<NPAD / 64, 256, 0, stream>>>(h, Wth1, Wtl1, xs1b,
                                                          as1, ad1, als1, ald1,
                                                          sum0, sq0, bng, bnb);
    k_aggregate<112, 1><<<AGG_NBLK, 256, 0, stream>>>(ordq, pk, als1, ald1, xs1b, out1, psum, psq);
    k_bn_stats2<<<128, 256, 0, stream>>>(psum, psq, sum1, sq1);
    k_bn_apply<112><<<(N * 112 / 4 + 255) / 256, 256, 0, stream>>>(out1, (float*)d_out, sum1, sq1, bnfg, bnfb, N);
}